// Round 4
// baseline (233.074 us; speedup 1.0000x reference)
//
#include <hip/hip_runtime.h>
#include <math.h>

#define NB 8
#define NS 512
#define NE 32
#define DE 256
#define DH 512
#define DA 200
#define DAP 224   // padded att dim (7 tiles of 32)
#define NJ 7

typedef __bf16 bf16x8 __attribute__((ext_vector_type(8)));
typedef float f32x16 __attribute__((ext_vector_type(16)));

__device__ __forceinline__ float tanh_fast(float x) {
    float e = __expf(2.f * x);
    return 1.f - 2.f / (e + 1.f);
}

// ---- stage 1: partial sums of cxt over s-chunks (512 blocks) ----
__global__ __launch_bounds__(256) void cmean_partial(const float* __restrict__ cxt,
                                                     float* __restrict__ psum) {
    const int g = blockIdx.x;       // b*64 + c
    const int b = g >> 6, c = g & 63;
    const int t = threadIdx.x;
    const float* base = cxt + ((size_t)b * NS + c * 8) * DH;
    float s0 = 0.f, s1 = 0.f;
    #pragma unroll
    for (int s = 0; s < 8; ++s) {
        s0 += base[s * DH + t];
        s1 += base[s * DH + t + 256];
    }
    psum[(size_t)g * DH + t]       = s0;
    psum[(size_t)g * DH + t + 256] = s1;
}

// ---- stage 2: reduce partials -> cmean; hatt[b][a] = cmean @ Wh (zero-padded) ----
__global__ __launch_bounds__(256) void hatt_from_psum(const float* __restrict__ psum,
                                                      const float* __restrict__ Wh,
                                                      float* __restrict__ hattw) {
    const int b = blockIdx.x;
    const int t = threadIdx.x;
    __shared__ float cm[DH];
    float s0 = 0.f, s1 = 0.f;
    for (int c = 0; c < 64; ++c) {
        s0 += psum[((size_t)b * 64 + c) * DH + t];
        s1 += psum[((size_t)b * 64 + c) * DH + t + 256];
    }
    cm[t]       = s0 * (1.f / NS);
    cm[t + 256] = s1 * (1.f / NS);
    __syncthreads();
    if (t < DAP) {
        float acc = 0.f;
        if (t < DA)
            for (int h = 0; h < DH; ++h)
                acc = fmaf(cm[h], Wh[h * DA + t], acc);
        hattw[b * DAP + t] = acc;
    }
}

// ---- stage 3: pack We into bf16 B-fragment layout (zero-padded cols) ----
// frag f = nj*16+kk; lane l, elem e: K = kk*16 + (l>>5)*4 + (e&3) + 8*(e>>2),
//                                    n = nj*32 + (l&31)
__global__ __launch_bounds__(64) void wef_build(const float* __restrict__ We,
                                                __bf16* __restrict__ wef) {
    const int f = blockIdx.x;
    const int l = threadIdx.x;
    const int nj = f >> 4, kk = f & 15;
    const int n = nj * 32 + (l & 31);
    bf16x8 v;
    #pragma unroll
    for (int e = 0; e < 8; ++e) {
        int K = kk * 16 + ((l >> 5) << 2) + (e & 3) + 8 * (e >> 2);
        v[e] = (__bf16)((n < DA) ? We[K * DA + n] : 0.f);
    }
    reinterpret_cast<bf16x8*>(wef)[f * 64 + l] = v;
}

// ---- per-tile compute: fully in-wave, no block barriers ----
__device__ __forceinline__ void process_tile(const bf16x8 (&A)[16],
                                             const bf16x8* __restrict__ wef8,
                                             const float* __restrict__ hb,
                                             const float* __restrict__ Ws,
                                             const float* __restrict__ eb,
                                             float* __restrict__ out,
                                             float (&lg_scratch)[NE],
                                             int bs, int lane) {
    const int m  = lane & 31;
    const int hi = lane >> 5;

    float part[16];
    #pragma unroll
    for (int r = 0; r < 16; ++r) part[r] = 0.f;

    #pragma unroll
    for (int nj = 0; nj < NJ; ++nj) {
        f32x16 acc;
        #pragma unroll
        for (int r = 0; r < 16; ++r) acc[r] = 0.f;
        #pragma unroll
        for (int kk = 0; kk < 16; ++kk)
            acc = __builtin_amdgcn_mfma_f32_32x32x16_bf16(
                      A[kk], wef8[(nj * 16 + kk) * 64 + lane], acc, 0, 0, 0);
        const int a   = nj * 32 + m;
        const float ha  = hb[a];
        const float wsa = (a < DA) ? Ws[a] : 0.f;
        #pragma unroll
        for (int r = 0; r < 16; ++r)
            part[r] = fmaf(tanh_fast(acc[r] + ha), wsa, part[r]);
    }

    // reduce over the 32 att-cols (lanes within 32-group)
    #pragma unroll
    for (int r = 0; r < 16; ++r) {
        float v = part[r];
        v += __shfl_xor(v, 1);  v += __shfl_xor(v, 2);  v += __shfl_xor(v, 4);
        v += __shfl_xor(v, 8);  v += __shfl_xor(v, 16);
        part[r] = v;
    }
    if (m == 0) {
        #pragma unroll
        for (int r = 0; r < 16; ++r)
            lg_scratch[(r & 3) + 8 * (r >> 2) + 4 * hi] = part[r];
    }
    // same-wave LDS RAW: compiler inserts lgkmcnt wait; no block barrier needed

    float lg[NE];
    float mx = -1e30f;
    #pragma unroll
    for (int e = 0; e < NE; ++e) { lg[e] = lg_scratch[e]; mx = fmaxf(mx, lg[e]); }
    float wsum = 0.f;
    #pragma unroll
    for (int e = 0; e < NE; ++e) { float w = __expf(lg[e] - mx); lg[e] = w; wsum += w; }
    const float inv = 1.f / wsum;

    const float4* eb4 = reinterpret_cast<const float4*>(eb);
    float4 o = make_float4(0.f, 0.f, 0.f, 0.f);
    #pragma unroll
    for (int e = 0; e < NE; ++e) {
        float4 v = eb4[e * 64 + lane];
        o.x = fmaf(lg[e], v.x, o.x); o.y = fmaf(lg[e], v.y, o.y);
        o.z = fmaf(lg[e], v.z, o.z); o.w = fmaf(lg[e], v.w, o.w);
    }
    float4 res = make_float4(o.x * inv, o.y * inv, o.z * inv, o.w * inv);
    reinterpret_cast<float4*>(out)[(size_t)bs * 64 + lane] = res;
}

// ---- main: barrier-free, one wave per 2 (b,s)-tiles, A resident in VGPRs ----
__global__ __launch_bounds__(256, 2) void entatt_main(const float* __restrict__ ent,
                                                      const __bf16* __restrict__ wef,
                                                      const float* __restrict__ hattw,
                                                      const float* __restrict__ Ws,
                                                      float* __restrict__ out) {
    const int t    = threadIdx.x;
    const int lane = t & 63;
    const int wid  = t >> 6;            // 0..3
    const int g    = blockIdx.x;        // 0..511
    const int bs0  = g * 8 + wid * 2;   // this wave: bs0, bs0+1
    const int b    = bs0 >> 9;

    __shared__ float lg_lds[4][NE];

    const int m  = lane & 31;
    const int hi = lane >> 5;

    const float* e0 = ent + (size_t)bs0 * (NE * DE);
    const float* e1 = e0 + NE * DE;

    // load A fragments for both tiles directly from global (64 x 16B in flight)
    bf16x8 A0[16], A1[16];
    #pragma unroll
    for (int kk = 0; kk < 16; ++kk) {
        const float* p = e0 + m * DE + kk * 16 + hi * 4;
        float4 u0 = *reinterpret_cast<const float4*>(p);
        float4 u1 = *reinterpret_cast<const float4*>(p + 8);
        bf16x8 v = { (__bf16)u0.x, (__bf16)u0.y, (__bf16)u0.z, (__bf16)u0.w,
                     (__bf16)u1.x, (__bf16)u1.y, (__bf16)u1.z, (__bf16)u1.w };
        A0[kk] = v;
    }
    #pragma unroll
    for (int kk = 0; kk < 16; ++kk) {
        const float* p = e1 + m * DE + kk * 16 + hi * 4;
        float4 u0 = *reinterpret_cast<const float4*>(p);
        float4 u1 = *reinterpret_cast<const float4*>(p + 8);
        bf16x8 v = { (__bf16)u0.x, (__bf16)u0.y, (__bf16)u0.z, (__bf16)u0.w,
                     (__bf16)u1.x, (__bf16)u1.y, (__bf16)u1.z, (__bf16)u1.w };
        A1[kk] = v;
    }

    const bf16x8* wef8 = reinterpret_cast<const bf16x8*>(wef);
    const float*  hb   = hattw + b * DAP;

    process_tile(A0, wef8, hb, Ws, e0, out, lg_lds[wid], bs0,     lane);
    process_tile(A1, wef8, hb, Ws, e1, out, lg_lds[wid], bs0 + 1, lane);
}

extern "C" void kernel_launch(void* const* d_in, const int* in_sizes, int n_in,
                              void* d_out, int out_size, void* d_ws, size_t ws_size,
                              hipStream_t stream) {
    const float* cxt = (const float*)d_in[0];
    const float* ent = (const float*)d_in[1];
    const float* We  = (const float*)d_in[2];
    const float* Wh  = (const float*)d_in[3];
    const float* Ws  = (const float*)d_in[4];
    float* out = (float*)d_out;

    float*  psum  = (float*)d_ws;                       // 512*512 f32 = 1 MB
    float*  hattw = psum + 512 * DH;                    // 8*224 f32
    __bf16* wef   = (__bf16*)(hattw + NB * DAP);        // 7*16*512 bf16 = 112 KB

    hipLaunchKernelGGL(wef_build, dim3(NJ * 16), dim3(64), 0, stream, We, wef);
    hipLaunchKernelGGL(cmean_partial, dim3(512), dim3(256), 0, stream, cxt, psum);
    hipLaunchKernelGGL(hatt_from_psum, dim3(NB), dim3(256), 0, stream, psum, Wh, hattw);
    hipLaunchKernelGGL(entatt_main, dim3(512), dim3(256), 0, stream,
                       ent, wef, hattw, Ws, out);
}

// Round 5
// 116.002 us; speedup vs baseline: 2.0092x; 2.0092x over previous
//
#include <hip/hip_runtime.h>
#include <math.h>

#define NB 8
#define NS 512
#define NE 32
#define DE 256
#define DH 512
#define DA 200
#define DAP 224   // padded att dim (7 tiles of 32)
#define NJ 7

typedef __bf16 bf16x8 __attribute__((ext_vector_type(8)));
typedef float f32x16 __attribute__((ext_vector_type(16)));

__device__ __forceinline__ float tanh_fast(float x) {
    float e = __expf(2.f * x);
    return 1.f - 2.f / (e + 1.f);
}

// ---- stage 1: partial sums of cxt over s-chunks (512 blocks) ----
__global__ __launch_bounds__(256) void cmean_partial(const float* __restrict__ cxt,
                                                     float* __restrict__ psum) {
    const int g = blockIdx.x;       // b*64 + c
    const int b = g >> 6, c = g & 63;
    const int t = threadIdx.x;
    const float* base = cxt + ((size_t)b * NS + c * 8) * DH;
    float s0 = 0.f, s1 = 0.f;
    #pragma unroll
    for (int s = 0; s < 8; ++s) {
        s0 += base[s * DH + t];
        s1 += base[s * DH + t + 256];
    }
    psum[(size_t)g * DH + t]       = s0;
    psum[(size_t)g * DH + t + 256] = s1;
}

// ---- stage 2: reduce partials -> cmean; hatt[b][a] = cmean @ Wh (zero-padded) ----
__global__ __launch_bounds__(256) void hatt_from_psum(const float* __restrict__ psum,
                                                      const float* __restrict__ Wh,
                                                      float* __restrict__ hattw) {
    const int b = blockIdx.x;
    const int t = threadIdx.x;
    __shared__ float cm[DH];
    float s0 = 0.f, s1 = 0.f;
    for (int c = 0; c < 64; ++c) {
        s0 += psum[((size_t)b * 64 + c) * DH + t];
        s1 += psum[((size_t)b * 64 + c) * DH + t + 256];
    }
    cm[t]       = s0 * (1.f / NS);
    cm[t + 256] = s1 * (1.f / NS);
    __syncthreads();
    if (t < DAP) {
        float acc = 0.f;
        if (t < DA)
            for (int h = 0; h < DH; ++h)
                acc = fmaf(cm[h], Wh[h * DA + t], acc);
        hattw[b * DAP + t] = acc;
    }
}

// ---- stage 3: pack We into bf16 B-fragment layout (zero-padded cols) ----
// frag f = nj*16+kk; lane l, elem e: K = kk*16 + (l>>5)*4 + (e&3) + 8*(e>>2),
//                                    n = nj*32 + (l&31)
__global__ __launch_bounds__(64) void wef_build(const float* __restrict__ We,
                                                __bf16* __restrict__ wef) {
    const int f = blockIdx.x;
    const int l = threadIdx.x;
    const int nj = f >> 4, kk = f & 15;
    const int n = nj * 32 + (l & 31);
    bf16x8 v;
    #pragma unroll
    for (int e = 0; e < 8; ++e) {
        int K = kk * 16 + ((l >> 5) << 2) + (e & 3) + 8 * (e >> 2);
        v[e] = (__bf16)((n < DA) ? We[K * DA + n] : 0.f);
    }
    reinterpret_cast<bf16x8*>(wef)[f * 64 + l] = v;
}

// ---- main: barrier-free, ONE (b,s)-tile per wave, A resident in VGPRs ----
// Register budget kept < ~140: A[16]=64 VGPRs, acc=16, part=16, no lg[] array
// (logits spilled to a 128B per-wave LDS scratch and re-streamed in epilogue).
__global__ __launch_bounds__(256) void entatt_main(const float* __restrict__ ent,
                                                   const __bf16* __restrict__ wef,
                                                   const float* __restrict__ hattw,
                                                   const float* __restrict__ Ws,
                                                   float* __restrict__ out) {
    const int t    = threadIdx.x;
    const int lane = t & 63;
    const int wid  = t >> 6;            // 0..3
    const int bs   = blockIdx.x * 4 + wid;
    const int b    = bs >> 9;           // NS=512

    __shared__ float lg_lds[4][NE];

    const int m  = lane & 31;
    const int hi = lane >> 5;

    const float* eb = ent + (size_t)bs * (NE * DE);

    // ---- A fragments straight from global (32 x 16B loads in flight) ----
    bf16x8 A[16];
    #pragma unroll
    for (int kk = 0; kk < 16; ++kk) {
        const float* p = eb + m * DE + kk * 16 + hi * 4;
        float4 u0 = *reinterpret_cast<const float4*>(p);
        float4 u1 = *reinterpret_cast<const float4*>(p + 8);
        bf16x8 v = { (__bf16)u0.x, (__bf16)u0.y, (__bf16)u0.z, (__bf16)u0.w,
                     (__bf16)u1.x, (__bf16)u1.y, (__bf16)u1.z, (__bf16)u1.w };
        A[kk] = v;
    }

    // per-lane att-column scalars for all 7 nj tiles (14 VGPRs)
    const float* hb = hattw + b * DAP;
    float ha_[NJ], wsa_[NJ];
    #pragma unroll
    for (int nj = 0; nj < NJ; ++nj) {
        const int a = nj * 32 + m;
        ha_[nj]  = hb[a];
        wsa_[nj] = (a < DA) ? Ws[a] : 0.f;
    }

    const bf16x8* wef8 = reinterpret_cast<const bf16x8*>(wef);

    // ---- MFMA + fused tanh/Ws partial logits; one acc live at a time ----
    float part[16];
    #pragma unroll
    for (int r = 0; r < 16; ++r) part[r] = 0.f;

    #pragma unroll 1
    for (int nj = 0; nj < NJ; ++nj) {
        f32x16 acc;
        #pragma unroll
        for (int r = 0; r < 16; ++r) acc[r] = 0.f;
        #pragma unroll
        for (int kk = 0; kk < 16; ++kk)
            acc = __builtin_amdgcn_mfma_f32_32x32x16_bf16(
                      A[kk], wef8[(nj * 16 + kk) * 64 + lane], acc, 0, 0, 0);
        const float ha = ha_[nj], wsa = wsa_[nj];
        #pragma unroll
        for (int r = 0; r < 16; ++r)
            part[r] = fmaf(tanh_fast(acc[r] + ha), wsa, part[r]);
    }

    // ---- reduce over the 32 att-cols (within 32-lane groups) ----
    #pragma unroll
    for (int r = 0; r < 16; ++r) {
        float v = part[r];
        v += __shfl_xor(v, 1);  v += __shfl_xor(v, 2);  v += __shfl_xor(v, 4);
        v += __shfl_xor(v, 8);  v += __shfl_xor(v, 16);
        part[r] = v;
    }
    if (m == 0) {
        #pragma unroll
        for (int r = 0; r < 16; ++r)
            lg_lds[wid][(r & 3) + 8 * (r >> 2) + 4 * hi] = part[r];
    }
    // same-wave LDS RAW: compiler inserts lgkmcnt wait; no block barrier needed

    // ---- softmax over entities (streamed from LDS, no register array) ----
    float mx = -1e30f;
    #pragma unroll
    for (int e = 0; e < NE; ++e) mx = fmaxf(mx, lg_lds[wid][e]);

    const float4* eb4 = reinterpret_cast<const float4*>(eb);
    float wsum = 0.f;
    float4 o = make_float4(0.f, 0.f, 0.f, 0.f);
    #pragma unroll
    for (int e = 0; e < NE; ++e) {
        float w = __expf(lg_lds[wid][e] - mx);
        wsum += w;
        float4 v = eb4[e * 64 + lane];
        o.x = fmaf(w, v.x, o.x); o.y = fmaf(w, v.y, o.y);
        o.z = fmaf(w, v.z, o.z); o.w = fmaf(w, v.w, o.w);
    }
    const float inv = 1.f / wsum;
    float4 res = make_float4(o.x * inv, o.y * inv, o.z * inv, o.w * inv);
    reinterpret_cast<float4*>(out)[(size_t)bs * 64 + lane] = res;
}

extern "C" void kernel_launch(void* const* d_in, const int* in_sizes, int n_in,
                              void* d_out, int out_size, void* d_ws, size_t ws_size,
                              hipStream_t stream) {
    const float* cxt = (const float*)d_in[0];
    const float* ent = (const float*)d_in[1];
    const float* We  = (const float*)d_in[2];
    const float* Wh  = (const float*)d_in[3];
    const float* Ws  = (const float*)d_in[4];
    float* out = (float*)d_out;

    float*  psum  = (float*)d_ws;                       // 512*512 f32 = 1 MB
    float*  hattw = psum + 512 * DH;                    // 8*224 f32
    __bf16* wef   = (__bf16*)(hattw + NB * DAP);        // 7*16*512 bf16 = 112 KB

    hipLaunchKernelGGL(wef_build, dim3(NJ * 16), dim3(64), 0, stream, We, wef);
    hipLaunchKernelGGL(cmean_partial, dim3(512), dim3(256), 0, stream, cxt, psum);
    hipLaunchKernelGGL(hatt_from_psum, dim3(NB), dim3(256), 0, stream, psum, Wh, hattw);
    hipLaunchKernelGGL(entatt_main, dim3(1024), dim3(256), 0, stream,
                       ent, wef, hattw, Ws, out);
}

// Round 6
// 88.700 us; speedup vs baseline: 2.6277x; 1.3078x over previous
//
#include <hip/hip_runtime.h>
#include <math.h>

#define NB 8
#define NS 512
#define NE 32
#define DE 256
#define DH 512
#define DA 200
#define DAP 224   // padded att dim (7 tiles of 32)
#define NJ 7

typedef __bf16 bf16x8 __attribute__((ext_vector_type(8)));
typedef float f32x16 __attribute__((ext_vector_type(16)));

__device__ __forceinline__ float tanh_fast(float x) {
    // tanh(x) = 1 - 2/(exp(2x)+1); raw v_rcp is plenty accurate for logits
    float e = __expf(x + x);
    return fmaf(-2.f, __builtin_amdgcn_rcpf(e + 1.f), 1.f);
}

// ---- stage 1: partial sums of cxt over s-chunks (512 blocks) ----
__global__ __launch_bounds__(256) void cmean_partial(const float* __restrict__ cxt,
                                                     float* __restrict__ psum) {
    const int g = blockIdx.x;       // b*64 + c
    const int b = g >> 6, c = g & 63;
    const int t = threadIdx.x;
    const float* base = cxt + ((size_t)b * NS + c * 8) * DH;
    float s0 = 0.f, s1 = 0.f;
    #pragma unroll
    for (int s = 0; s < 8; ++s) {
        s0 += base[s * DH + t];
        s1 += base[s * DH + t + 256];
    }
    psum[(size_t)g * DH + t]       = s0;
    psum[(size_t)g * DH + t + 256] = s1;
}

// ---- stage 2: reduce partials -> cmean; hatt[b][a] = cmean @ Wh (zero-padded) ----
__global__ __launch_bounds__(256) void hatt_from_psum(const float* __restrict__ psum,
                                                      const float* __restrict__ Wh,
                                                      float* __restrict__ hattw) {
    const int b = blockIdx.x;
    const int t = threadIdx.x;
    __shared__ float cm[DH];
    float s0 = 0.f, s1 = 0.f;
    for (int c = 0; c < 64; ++c) {
        s0 += psum[((size_t)b * 64 + c) * DH + t];
        s1 += psum[((size_t)b * 64 + c) * DH + t + 256];
    }
    cm[t]       = s0 * (1.f / NS);
    cm[t + 256] = s1 * (1.f / NS);
    __syncthreads();
    if (t < DAP) {
        float acc = 0.f;
        if (t < DA)
            for (int h = 0; h < DH; ++h)
                acc = fmaf(cm[h], Wh[h * DA + t], acc);
        hattw[b * DAP + t] = acc;
    }
}

// ---- stage 3: pack We into bf16 B-fragment layout (zero-padded cols) ----
// frag f = nj*16+kk; lane l, elem e: K = kk*16 + (l>>5)*4 + (e&3) + 8*(e>>2),
//                                    n = nj*32 + (l&31)
__global__ __launch_bounds__(64) void wef_build(const float* __restrict__ We,
                                                __bf16* __restrict__ wef) {
    const int f = blockIdx.x;
    const int l = threadIdx.x;
    const int nj = f >> 4, kk = f & 15;
    const int n = nj * 32 + (l & 31);
    bf16x8 v;
    #pragma unroll
    for (int e = 0; e < 8; ++e) {
        int K = kk * 16 + ((l >> 5) << 2) + (e & 3) + 8 * (e >> 2);
        v[e] = (__bf16)((n < DA) ? We[K * DA + n] : 0.f);
    }
    reinterpret_cast<bf16x8*>(wef)[f * 64 + l] = v;
}

// ---- per-tile compute: fully in-wave, wef read from LDS ----
__device__ __forceinline__ void process_tile(const bf16x8 (&A)[16],
                                             const __bf16* __restrict__ wef_lds,
                                             const float (&ha_)[NJ],
                                             const float (&wsa_)[NJ],
                                             const float* __restrict__ eb,
                                             float* __restrict__ out,
                                             float* __restrict__ lg_scratch,
                                             int bs, int lane) {
    const int m  = lane & 31;
    const int hi = lane >> 5;
    const bf16x8* w8 = reinterpret_cast<const bf16x8*>(wef_lds);

    float part[16];
    #pragma unroll
    for (int r = 0; r < 16; ++r) part[r] = 0.f;

    #pragma unroll 1
    for (int nj = 0; nj < NJ; ++nj) {
        f32x16 accA, accB;
        #pragma unroll
        for (int r = 0; r < 16; ++r) { accA[r] = 0.f; accB[r] = 0.f; }
        #pragma unroll
        for (int kk = 0; kk < 16; kk += 2) {
            accA = __builtin_amdgcn_mfma_f32_32x32x16_bf16(
                       A[kk],     w8[(nj * 16 + kk) * 64 + lane],     accA, 0, 0, 0);
            accB = __builtin_amdgcn_mfma_f32_32x32x16_bf16(
                       A[kk + 1], w8[(nj * 16 + kk + 1) * 64 + lane], accB, 0, 0, 0);
        }
        const float ha = ha_[nj], wsa = wsa_[nj];
        #pragma unroll
        for (int r = 0; r < 16; ++r)
            part[r] = fmaf(tanh_fast(accA[r] + accB[r] + ha), wsa, part[r]);
    }

    // reduce over the 32 att-cols (within 32-lane groups)
    #pragma unroll
    for (int r = 0; r < 16; ++r) {
        float v = part[r];
        v += __shfl_xor(v, 1);  v += __shfl_xor(v, 2);  v += __shfl_xor(v, 4);
        v += __shfl_xor(v, 8);  v += __shfl_xor(v, 16);
        part[r] = v;
    }
    if (m == 0) {
        #pragma unroll
        for (int r = 0; r < 16; ++r)
            lg_scratch[(r & 3) + 8 * (r >> 2) + 4 * hi] = part[r];
    }
    // same-wave LDS RAW: compiler inserts lgkmcnt wait; no block barrier needed

    float mx = -1e30f;
    #pragma unroll
    for (int e = 0; e < NE; ++e) mx = fmaxf(mx, lg_scratch[e]);

    const float4* eb4 = reinterpret_cast<const float4*>(eb);
    float wsum = 0.f;
    float4 o = make_float4(0.f, 0.f, 0.f, 0.f);
    #pragma unroll
    for (int e = 0; e < NE; ++e) {
        float w = __expf(lg_scratch[e] - mx);
        wsum += w;
        float4 v = eb4[e * 64 + lane];
        o.x = fmaf(w, v.x, o.x); o.y = fmaf(w, v.y, o.y);
        o.z = fmaf(w, v.z, o.z); o.w = fmaf(w, v.w, o.w);
    }
    const float inv = __builtin_amdgcn_rcpf(wsum);
    float4 res = make_float4(o.x * inv, o.y * inv, o.z * inv, o.w * inv);
    reinterpret_cast<float4*>(out)[(size_t)bs * 64 + lane] = res;
}

// ---- main: 8 waves/block, wef staged to LDS once, 2 tiles per wave ----
__global__ __launch_bounds__(512, 2) void entatt_main(const float* __restrict__ ent,
                                                      const __bf16* __restrict__ wef,
                                                      const float* __restrict__ hattw,
                                                      const float* __restrict__ Ws,
                                                      float* __restrict__ out) {
    const int t    = threadIdx.x;
    const int lane = t & 63;
    const int wid  = t >> 6;            // 0..7
    const int g    = blockIdx.x;        // 0..255
    const int bs0  = g * 16 + wid * 2;  // this wave: bs0, bs0+1
    const int b    = g >> 5;            // 32 blocks per batch

    __shared__ __bf16 wef_lds[NJ * 16 * 512];   // 112 KB
    __shared__ float  lg_lds[8][NE];

    // ---- stage wef -> LDS (coalesced 16B, once per block) ----
    {
        const float4* s4 = reinterpret_cast<const float4*>(wef);
        float4* d4 = reinterpret_cast<float4*>(wef_lds);
        #pragma unroll
        for (int i = 0; i < 14; ++i) d4[t + i * 512] = s4[t + i * 512];
    }

    const int m  = lane & 31;
    const int hi = lane >> 5;
    const float* e0 = ent + (size_t)bs0 * (NE * DE);
    const float* e1 = e0 + NE * DE;

    // ---- A fragments for both tiles straight from global ----
    bf16x8 A0[16], A1[16];
    #pragma unroll
    for (int kk = 0; kk < 16; ++kk) {
        const float* p = e0 + m * DE + kk * 16 + hi * 4;
        float4 u0 = *reinterpret_cast<const float4*>(p);
        float4 u1 = *reinterpret_cast<const float4*>(p + 8);
        bf16x8 v = { (__bf16)u0.x, (__bf16)u0.y, (__bf16)u0.z, (__bf16)u0.w,
                     (__bf16)u1.x, (__bf16)u1.y, (__bf16)u1.z, (__bf16)u1.w };
        A0[kk] = v;
    }
    #pragma unroll
    for (int kk = 0; kk < 16; ++kk) {
        const float* p = e1 + m * DE + kk * 16 + hi * 4;
        float4 u0 = *reinterpret_cast<const float4*>(p);
        float4 u1 = *reinterpret_cast<const float4*>(p + 8);
        bf16x8 v = { (__bf16)u0.x, (__bf16)u0.y, (__bf16)u0.z, (__bf16)u0.w,
                     (__bf16)u1.x, (__bf16)u1.y, (__bf16)u1.z, (__bf16)u1.w };
        A1[kk] = v;
    }

    // per-lane att-column scalars for all 7 nj tiles
    const float* hb = hattw + b * DAP;
    float ha_[NJ], wsa_[NJ];
    #pragma unroll
    for (int nj = 0; nj < NJ; ++nj) {
        const int a = nj * 32 + m;
        ha_[nj]  = hb[a];
        wsa_[nj] = (a < DA) ? Ws[a] : 0.f;
    }

    __syncthreads();   // wef_lds ready (also drains A-load vmcnt — harmless)

    process_tile(A0, wef_lds, ha_, wsa_, e0, out, lg_lds[wid], bs0,     lane);
    process_tile(A1, wef_lds, ha_, wsa_, e1, out, lg_lds[wid], bs0 + 1, lane);
}

extern "C" void kernel_launch(void* const* d_in, const int* in_sizes, int n_in,
                              void* d_out, int out_size, void* d_ws, size_t ws_size,
                              hipStream_t stream) {
    const float* cxt = (const float*)d_in[0];
    const float* ent = (const float*)d_in[1];
    const float* We  = (const float*)d_in[2];
    const float* Wh  = (const float*)d_in[3];
    const float* Ws  = (const float*)d_in[4];
    float* out = (float*)d_out;

    float*  psum  = (float*)d_ws;                       // 512*512 f32 = 1 MB
    float*  hattw = psum + 512 * DH;                    // 8*224 f32
    __bf16* wef   = (__bf16*)(hattw + NB * DAP);        // 7*16*512 bf16 = 112 KB

    hipLaunchKernelGGL(wef_build, dim3(NJ * 16), dim3(64), 0, stream, We, wef);
    hipLaunchKernelGGL(cmean_partial, dim3(512), dim3(256), 0, stream, cxt, psum);
    hipLaunchKernelGGL(hatt_from_psum, dim3(NB), dim3(256), 0, stream, psum, Wh, hattw);
    hipLaunchKernelGGL(entatt_main, dim3(256), dim3(512), 0, stream,
                       ent, wef, hattw, Ws, out);
}

// Round 7
// 88.450 us; speedup vs baseline: 2.6351x; 1.0028x over previous
//
#include <hip/hip_runtime.h>
#include <math.h>

#define NB 8
#define NS 512
#define NE 32
#define DE 256
#define DH 512
#define DA 200
#define DAP 224   // padded att dim (7 tiles of 32)
#define NJ 7

typedef __bf16 bf16x8 __attribute__((ext_vector_type(8)));
typedef float f32x16 __attribute__((ext_vector_type(16)));

__device__ __forceinline__ float tanh_fast(float x) {
    // tanh(x) = 1 - 2/(exp(2x)+1); raw v_rcp is plenty accurate for logits
    float e = __expf(x + x);
    return fmaf(-2.f, __builtin_amdgcn_rcpf(e + 1.f), 1.f);
}

// ---- stage 1: partial sums of cxt over s-chunks (512 blocks) ----
__global__ __launch_bounds__(256) void cmean_partial(const float* __restrict__ cxt,
                                                     float* __restrict__ psum) {
    const int g = blockIdx.x;       // b*64 + c
    const int b = g >> 6, c = g & 63;
    const int t = threadIdx.x;
    const float* base = cxt + ((size_t)b * NS + c * 8) * DH;
    float s0 = 0.f, s1 = 0.f;
    #pragma unroll
    for (int s = 0; s < 8; ++s) {
        s0 += base[s * DH + t];
        s1 += base[s * DH + t + 256];
    }
    psum[(size_t)g * DH + t]       = s0;
    psum[(size_t)g * DH + t + 256] = s1;
}

// ---- stage 2: reduce partials -> cmean; hatt[b][a] = cmean @ Wh (zero-padded) ----
__global__ __launch_bounds__(256) void hatt_from_psum(const float* __restrict__ psum,
                                                      const float* __restrict__ Wh,
                                                      float* __restrict__ hattw) {
    const int b = blockIdx.x;
    const int t = threadIdx.x;
    __shared__ float cm[DH];
    float s0 = 0.f, s1 = 0.f;
    for (int c = 0; c < 64; ++c) {
        s0 += psum[((size_t)b * 64 + c) * DH + t];
        s1 += psum[((size_t)b * 64 + c) * DH + t + 256];
    }
    cm[t]       = s0 * (1.f / NS);
    cm[t + 256] = s1 * (1.f / NS);
    __syncthreads();
    if (t < DAP) {
        float acc = 0.f;
        if (t < DA)
            for (int h = 0; h < DH; ++h)
                acc = fmaf(cm[h], Wh[h * DA + t], acc);
        hattw[b * DAP + t] = acc;
    }
}

// ---- stage 3: pack We into bf16 B-fragment layout (zero-padded cols) ----
// frag f = nj*16+kk; lane l, elem e: K = kk*16 + (l>>5)*4 + (e&3) + 8*(e>>2),
//                                    n = nj*32 + (l&31)
__global__ __launch_bounds__(64) void wef_build(const float* __restrict__ We,
                                                __bf16* __restrict__ wef) {
    const int f = blockIdx.x;
    const int l = threadIdx.x;
    const int nj = f >> 4, kk = f & 15;
    const int n = nj * 32 + (l & 31);
    bf16x8 v;
    #pragma unroll
    for (int e = 0; e < 8; ++e) {
        int K = kk * 16 + ((l >> 5) << 2) + (e & 3) + 8 * (e >> 2);
        v[e] = (__bf16)((n < DA) ? We[K * DA + n] : 0.f);
    }
    reinterpret_cast<bf16x8*>(wef)[f * 64 + l] = v;
}

// ---- main: 8 waves/block, wef in LDS, ONE tile per wave (no-spill shape) ----
__global__ __launch_bounds__(512, 2) void entatt_main(const float* __restrict__ ent,
                                                      const __bf16* __restrict__ wef,
                                                      const float* __restrict__ hattw,
                                                      const float* __restrict__ Ws,
                                                      float* __restrict__ out) {
    const int t    = threadIdx.x;
    const int lane = t & 63;
    const int wid  = t >> 6;            // 0..7
    const int g    = blockIdx.x;        // 0..511
    const int bs   = g * 8 + wid;       // one tile per wave
    const int b    = g >> 6;            // 64 blocks per batch

    __shared__ __bf16 wef_lds[NJ * 16 * 512];   // 112 KB
    __shared__ float  lg_lds[8][NE];

    // ---- stage wef -> LDS (coalesced 16B, once per block) ----
    {
        const float4* s4 = reinterpret_cast<const float4*>(wef);
        float4* d4 = reinterpret_cast<float4*>(wef_lds);
        #pragma unroll
        for (int i = 0; i < 14; ++i) d4[t + i * 512] = s4[t + i * 512];
    }

    const int m  = lane & 31;
    const int hi = lane >> 5;
    const float* eb = ent + (size_t)bs * (NE * DE);

    // ---- A fragments straight from global (32 x 16B in flight, overlaps staging) ----
    bf16x8 A[16];
    #pragma unroll
    for (int kk = 0; kk < 16; ++kk) {
        const float* p = eb + m * DE + kk * 16 + hi * 4;
        float4 u0 = *reinterpret_cast<const float4*>(p);
        float4 u1 = *reinterpret_cast<const float4*>(p + 8);
        bf16x8 v = { (__bf16)u0.x, (__bf16)u0.y, (__bf16)u0.z, (__bf16)u0.w,
                     (__bf16)u1.x, (__bf16)u1.y, (__bf16)u1.z, (__bf16)u1.w };
        A[kk] = v;
    }

    // per-lane att-column scalars for all 7 nj tiles
    const float* hb = hattw + b * DAP;
    float ha_[NJ], wsa_[NJ];
    #pragma unroll
    for (int nj = 0; nj < NJ; ++nj) {
        const int a = nj * 32 + m;
        ha_[nj]  = hb[a];
        wsa_[nj] = (a < DA) ? Ws[a] : 0.f;
    }

    __syncthreads();   // wef_lds ready

    const bf16x8* w8 = reinterpret_cast<const bf16x8*>(wef_lds);

    // ---- MFMA + fused tanh/Ws partial logits; single acc live at a time ----
    float part[16];
    #pragma unroll
    for (int r = 0; r < 16; ++r) part[r] = 0.f;

    #pragma unroll 1
    for (int nj = 0; nj < NJ; ++nj) {
        f32x16 acc;
        #pragma unroll
        for (int r = 0; r < 16; ++r) acc[r] = 0.f;
        #pragma unroll
        for (int kk = 0; kk < 16; ++kk)
            acc = __builtin_amdgcn_mfma_f32_32x32x16_bf16(
                      A[kk], w8[(nj * 16 + kk) * 64 + lane], acc, 0, 0, 0);
        const float ha = ha_[nj], wsa = wsa_[nj];
        #pragma unroll
        for (int r = 0; r < 16; ++r)
            part[r] = fmaf(tanh_fast(acc[r] + ha), wsa, part[r]);
    }

    // ---- reduce over the 32 att-cols (within 32-lane groups) ----
    #pragma unroll
    for (int r = 0; r < 16; ++r) {
        float v = part[r];
        v += __shfl_xor(v, 1);  v += __shfl_xor(v, 2);  v += __shfl_xor(v, 4);
        v += __shfl_xor(v, 8);  v += __shfl_xor(v, 16);
        part[r] = v;
    }
    if (m == 0) {
        #pragma unroll
        for (int r = 0; r < 16; ++r)
            lg_lds[wid][(r & 3) + 8 * (r >> 2) + 4 * hi] = part[r];
    }
    // same-wave LDS RAW: compiler inserts lgkmcnt wait; no block barrier needed

    // ---- softmax over entities (streamed from LDS) + fp32 weighted sum ----
    float mx = -1e30f;
    #pragma unroll
    for (int e = 0; e < NE; ++e) mx = fmaxf(mx, lg_lds[wid][e]);

    const float4* eb4 = reinterpret_cast<const float4*>(eb);
    float wsum = 0.f;
    float4 o = make_float4(0.f, 0.f, 0.f, 0.f);
    #pragma unroll
    for (int e = 0; e < NE; ++e) {
        float w = __expf(lg_lds[wid][e] - mx);
        wsum += w;
        float4 v = eb4[e * 64 + lane];
        o.x = fmaf(w, v.x, o.x); o.y = fmaf(w, v.y, o.y);
        o.z = fmaf(w, v.z, o.z); o.w = fmaf(w, v.w, o.w);
    }
    const float inv = __builtin_amdgcn_rcpf(wsum);
    float4 res = make_float4(o.x * inv, o.y * inv, o.z * inv, o.w * inv);
    reinterpret_cast<float4*>(out)[(size_t)bs * 64 + lane] = res;
}

extern "C" void kernel_launch(void* const* d_in, const int* in_sizes, int n_in,
                              void* d_out, int out_size, void* d_ws, size_t ws_size,
                              hipStream_t stream) {
    const float* cxt = (const float*)d_in[0];
    const float* ent = (const float*)d_in[1];
    const float* We  = (const float*)d_in[2];
    const float* Wh  = (const float*)d_in[3];
    const float* Ws  = (const float*)d_in[4];
    float* out = (float*)d_out;

    float*  psum  = (float*)d_ws;                       // 512*512 f32 = 1 MB
    float*  hattw = psum + 512 * DH;                    // 8*224 f32
    __bf16* wef   = (__bf16*)(hattw + NB * DAP);        // 7*16*512 bf16 = 112 KB

    hipLaunchKernelGGL(wef_build, dim3(NJ * 16), dim3(64), 0, stream, We, wef);
    hipLaunchKernelGGL(cmean_partial, dim3(512), dim3(256), 0, stream, cxt, psum);
    hipLaunchKernelGGL(hatt_from_psum, dim3(NB), dim3(256), 0, stream, psum, Wh, hattw);
    hipLaunchKernelGGL(entatt_main, dim3(512), dim3(512), 0, stream,
                       ent, wef, hattw, Ws, out);
}